// Round 6
// baseline (3993.152 us; speedup 1.0000x reference)
//
#include <hip/hip_runtime.h>
#include <hip/hip_bf16.h>

// KWSNet: conv1d+relu -> 2x GRU (fwd-scan, two weight sets) -> sliding mean -> linear(2)
// B=64, M=80, T=2000, C=H=256, K=5; Tc=1996, W=96, Tout=1901, out (1901,1,64,2) fp32.
//
// Chunked pipeline (8 x <=250 steps): conv -> proj (fp16 MFMA) -> persistent GRU
// scan (AGPR-resident weights) -> clf -> final.
//
// R18: weight-delivery tier tally: L2 reload 185us (R12), LDS 237us (R17,
// LDS-issue-bound: 4 waves x 48 ds_read_b128 x ~12cyc = 2300 cyc/step), scratch
// 246us (R13/R16). Registers are the only fast tier; allocator caps VGPRs ~132.
// gfx950's 256 AGPRs/wave sit idle in this MFMA-free kernel -> store gates r,z
// (128 dwords) in EXPLICIT AGPRs a0-a127 via inline asm accvgpr_write/read with
// per-access "aN" clobbers (backend allocates them; values never enter the
// allocator's domain -> cannot spill/remat). Gate n stays in 16 pinned-VGPR
// uint4 (R17 proved resident: 132 = 64 + 68 working).
// Per-step: 128 accvgpr_read + 192 sdot + gates ~= 700 VALU cyc; LDS only 16
// h-broadcasts. Predict scan 237 -> 75-100us, LDS 512B, VALUBusy 50-70%.
// Falsify: >=150us => all storage tiers exhausted -> roofline.

#define TT    2000
#define TC    1996
#define NB    64
#define MCH   80
#define NH    256
#define NN    1536           // 2 * 3H
#define TOUT  1901
#define TCH   250            // chunk length (last chunk = 246)
#define NCHK  8
#define CROWS (TCH * NB)     // 16000 rows per chunk

typedef _Float16 h2_t __attribute__((ext_vector_type(2)));
typedef _Float16 h8_t __attribute__((ext_vector_type(8)));
typedef float    f4_t __attribute__((ext_vector_type(4)));

#define WQSCALE 254.0f
#define INV8    (1.0f / (254.0f * 127.0f))

// ---------------- workspace layout (bytes), total ~76.5 MB ----------------
#define OFF_SEQC ((size_t)0)            // fp16 [CROWS][256]      = 8,192,000
#define OFF_XG   ((size_t)8192000)      // fp16 [2][CROWS][768]   = 49,152,000
#define OFF_WT   ((size_t)57344000)     // fp32 [400][256]        = 409,600
#define OFF_WCAT ((size_t)57753600)     // fp16 [1536][256]       = 786,432
#define OFF_PSUM ((size_t)58540032)     // fp32 [TC][64][2]       = 1,021,952
#define OFF_HST  ((size_t)59561984)     // fp32 [128][256]        = 131,072
#define OFF_WQ   ((size_t)59693056)     // u32  [2][3][256][64]   = 393,216  (int8 W_hh, all cols)
#define OFF_ENC  ((size_t)60086272)     // fp16 [TCH*64][512]     = 16,384,000

// ---------------- prep: transpose conv_w, fp16 w_ih concat, int8-quantize W_hh ----------------
__global__ void prep_kernel(const float* __restrict__ conv_w,
                            const float* __restrict__ wihf,
                            const float* __restrict__ wihr,
                            const float* __restrict__ whhf,
                            const float* __restrict__ whhr,
                            float* __restrict__ wT,
                            _Float16* __restrict__ wcat,
                            unsigned* __restrict__ wq) {
    int idx = blockIdx.x * 256 + threadIdx.x;
    if (idx < 400 * 256) {
        int c = idx & 255, mk = idx >> 8;
        wT[idx] = conv_w[c * 400 + mk];
    }
    int i2 = idx - 400 * 256;
    if (i2 >= 0 && i2 < NN * 256) {
        int k = i2 & 255, n = i2 >> 8;
        float v = (n < 768) ? wihf[n * 256 + k] : wihr[(n - 768) * 256 + k];
        wcat[i2] = (_Float16)v;
    }
    int i4 = idx - (400 * 256 + NN * 256);
    if (i4 >= 0 && i4 < 2 * 3 * 256 * 64) {
        // element (d,g,r,j): uint packs cols 4j..4j+3 of row g*256+r of whh_d
        int r  = i4 & 255;
        int j  = (i4 >> 8) & 63;
        int dg = i4 >> 14;               // 0..5 = d*3+g
        const float* whh = (dg >= 3) ? whhr : whhf;
        int g = (dg >= 3) ? dg - 3 : dg;
        const float* wp = whh + (size_t)(g * 256 + r) * 256 + 4 * j;
        unsigned v = 0;
#pragma unroll
        for (int kk = 0; kk < 4; ++kk) {
            float q = rintf(wp[kk] * WQSCALE);
            q = fminf(fmaxf(q, -127.f), 127.f);
            v |= ((unsigned)((int)q & 0xFF)) << (8 * kk);
        }
        wq[((size_t)dg * 256 + r) * 64 + j] = v;
    }
}

// ---------------- conv1d(valid,K=5)+bias+relu -> seqc fp16 [t_local*64+b][c] ----------------
__global__ __launch_bounds__(256, 2)
void conv_kernel(const float* __restrict__ x, const float* __restrict__ wT,
                 const float* __restrict__ conv_b, _Float16* __restrict__ seqc,
                 int t_base, int t_len) {
    __shared__ float xs[MCH][68];
    int tile = blockIdx.x;           // 0..3
    int b    = blockIdx.y;           // 0..63
    int tid  = threadIdx.x;
    for (int idx = tid; idx < MCH * 68; idx += 256) {
        int m = idx / 68, i = idx - m * 68;
        int tt = t_base + tile * 64 + i;
        xs[m][i] = (tt < TT) ? x[(size_t)b * (MCH * TT) + m * TT + tt] : 0.f;
    }
    __syncthreads();
    int lane = tid & 63, tg = tid >> 6;   // wave tg: t-range [tg*16, tg*16+16)
    float acc[4][16];
#pragma unroll
    for (int cq = 0; cq < 4; ++cq)
#pragma unroll
        for (int t = 0; t < 16; ++t) acc[cq][t] = 0.f;

    for (int m = 0; m < MCH; ++m) {
        float xr_[20];
#pragma unroll
        for (int q = 0; q < 5; ++q) {
            float4 v = *(const float4*)&xs[m][tg * 16 + q * 4];
            xr_[q * 4 + 0] = v.x; xr_[q * 4 + 1] = v.y;
            xr_[q * 4 + 2] = v.z; xr_[q * 4 + 3] = v.w;
        }
#pragma unroll
        for (int cq = 0; cq < 4; ++cq) {
            int c = lane + cq * 64;
            const float* wp = wT + (size_t)(m * 5) * 256 + c;
            float w0_ = wp[0], w1_ = wp[256], w2_ = wp[512], w3_ = wp[768], w4_ = wp[1024];
#pragma unroll
            for (int t = 0; t < 16; ++t)
                acc[cq][t] += w0_ * xr_[t] + w1_ * xr_[t + 1] + w2_ * xr_[t + 2]
                            + w3_ * xr_[t + 3] + w4_ * xr_[t + 4];
        }
    }
#pragma unroll
    for (int cq = 0; cq < 4; ++cq) {
        int c = lane + cq * 64;
        float cb = conv_b[c];
        for (int t = 0; t < 16; ++t) {
            int tl = tile * 64 + tg * 16 + t;     // t within chunk
            if (tl < t_len) {
                float v = acc[cq][t] + cb;
                v = v > 0.f ? v : 0.f;
                seqc[((size_t)tl * 64 + b) * 256 + c] = (_Float16)v;
            }
        }
    }
}

// ---------------- proj: xg[d][row][j] = seqc @ w_ih^T + b_ih (fp16 MFMA 16x16x32) ----------------
__global__ __launch_bounds__(256, 2)
void proj_kernel(const _Float16* __restrict__ seqc, const _Float16* __restrict__ wcat,
                 const float* __restrict__ bihf, const float* __restrict__ bihr,
                 _Float16* __restrict__ xg) {
    __shared__ __align__(16) _Float16 As[128][72];
    __shared__ __align__(16) _Float16 Bs[128][72];
    int row0 = blockIdx.x * 128;     // up to 125 tiles
    int n0   = blockIdx.y * 128;     // 12 tiles
    int tid  = threadIdx.x;
    int lane = tid & 63, wv = tid >> 6;
    int wr = wv >> 1, wc = wv & 1;                 // 2x2 waves of 64x64
    int fm = lane & 15, fq = lane >> 4;            // fragment index, quad
    f4_t acc[4][4];
#pragma unroll
    for (int mt = 0; mt < 4; ++mt)
#pragma unroll
        for (int nt = 0; nt < 4; ++nt) acc[mt][nt] = (f4_t){0.f, 0.f, 0.f, 0.f};

    int r = tid >> 1, part = tid & 1;
    for (int kc = 0; kc < 4; ++kc) {
        const uint4* srcA = (const uint4*)&seqc[(size_t)(row0 + r) * 256 + kc * 64 + part * 32];
        const uint4* srcB = (const uint4*)&wcat[(size_t)(n0 + r) * 256 + kc * 64 + part * 32];
        uint4* dstA = (uint4*)&As[r][part * 32];
        uint4* dstB = (uint4*)&Bs[r][part * 32];
        dstA[0] = srcA[0]; dstA[1] = srcA[1]; dstA[2] = srcA[2]; dstA[3] = srcA[3];
        dstB[0] = srcB[0]; dstB[1] = srcB[1]; dstB[2] = srcB[2]; dstB[3] = srcB[3];
        __syncthreads();
#pragma unroll
        for (int ks = 0; ks < 64; ks += 32) {
            h8_t af[4], bf[4];
#pragma unroll
            for (int mt = 0; mt < 4; ++mt)
                af[mt] = *(const h8_t*)&As[wr * 64 + mt * 16 + fm][ks + fq * 8];
#pragma unroll
            for (int nt = 0; nt < 4; ++nt)
                bf[nt] = *(const h8_t*)&Bs[wc * 64 + nt * 16 + fm][ks + fq * 8];
#pragma unroll
            for (int mt = 0; mt < 4; ++mt)
#pragma unroll
                for (int nt = 0; nt < 4; ++nt)
                    acc[mt][nt] = __builtin_amdgcn_mfma_f32_16x16x32_f16(
                        af[mt], bf[nt], acc[mt][nt], 0, 0, 0);
        }
        __syncthreads();
    }
    // epilogue: C col = lane&15 (n-dim), row = (lane>>4)*4 + reg (m-dim)
#pragma unroll
    for (int nt = 0; nt < 4; ++nt) {
        int col = n0 + wc * 64 + nt * 16 + fm;
        int d = (col < 768) ? 0 : 1;
        int j = col - d * 768;
        float bias = d ? bihr[j] : bihf[j];
        size_t obase = (size_t)d * CROWS * 768 + j;
#pragma unroll
        for (int mt = 0; mt < 4; ++mt) {
            int row = row0 + wr * 64 + mt * 16 + fq * 4;
#pragma unroll
            for (int rr = 0; rr < 4; ++rr)
                xg[obase + (size_t)(row + rr) * 768] = (_Float16)(acc[mt][nt][rr] + bias);
        }
    }
}

// ---------------- persistent GRU scan chunk: 1 block (256 thr) per (direction, batch) ----------------
// Gates r,z: int8 rows in explicit AGPRs a0-a127 (inline asm, allocator-proof).
// Gate n: 16 pinned-VGPR uint4. h broadcast via 512B LDS double buffer.
#define SD4(a, b, c) __builtin_amdgcn_sdot4((int)(a), (int)(b), (c), false)
#define PIN4(v) asm volatile("" : "+v"((v).x), "+v"((v).y), "+v"((v).z), "+v"((v).w))
// explicit AGPR write/read; "aN" clobber makes the backend allocate + avoid it
#define AW(N, V) asm volatile("v_accvgpr_write_b32 a" #N ", %0" :: "v"(V) : "a" #N)
#define AR(N, D) asm volatile("v_accvgpr_read_b32 %0, a" #N : "=v"(D) :: "a" #N)

#define WINIT(K, R0,R1,R2,R3, Z0,Z1,Z2,Z3) { \
    uint4 r_ = pr[K], z_ = pz[K]; \
    AW(R0, r_.x); AW(R1, r_.y); AW(R2, r_.z); AW(R3, r_.w); \
    AW(Z0, z_.x); AW(Z1, z_.y); AW(Z2, z_.z); AW(Z3, z_.w); }

#define KSTEP(K, R0,R1,R2,R3, Z0,Z1,Z2,Z3) { \
    uint4 hv = hqp[K]; unsigned t0_, t1_, t2_, t3_; \
    AR(R0, t0_); AR(R1, t1_); AR(R2, t2_); AR(R3, t3_); \
    i0 = SD4(t0_, hv.x, i0); i0 = SD4(t1_, hv.y, i0); \
    i0 = SD4(t2_, hv.z, i0); i0 = SD4(t3_, hv.w, i0); \
    AR(Z0, t0_); AR(Z1, t1_); AR(Z2, t2_); AR(Z3, t3_); \
    i1 = SD4(t0_, hv.x, i1); i1 = SD4(t1_, hv.y, i1); \
    i1 = SD4(t2_, hv.z, i1); i1 = SD4(t3_, hv.w, i1); \
    i2 = SD4(wn[K].x, hv.x, i2); i2 = SD4(wn[K].y, hv.y, i2); \
    i2 = SD4(wn[K].z, hv.z, i2); i2 = SD4(wn[K].w, hv.w, i2); }

__global__ __launch_bounds__(256)
void scan_kernel(const _Float16* __restrict__ xg, const uint4* __restrict__ wq,
                 const float* __restrict__ bhhf, const float* __restrict__ bhhr,
                 float* __restrict__ hstate, _Float16* __restrict__ encc,
                 int t0, int len, int first) {
    int blk = blockIdx.x;
    int d = blk >> 6, b = blk & 63;
    int i = threadIdx.x;
    const float* bhh = d ? bhhr : bhhf;

    __shared__ __align__(16) unsigned hq8[2][64];   // int8 h, double-buffered (512 B)

    // stage: r,z -> AGPRs a0..a127; n -> pinned VGPRs
    uint4 wn[16];
    {
        const uint4* pr = wq + ((size_t)(d * 3 + 0) * 256 + i) * 16;
        const uint4* pz = wq + ((size_t)(d * 3 + 1) * 256 + i) * 16;
        const uint4* pn = wq + ((size_t)(d * 3 + 2) * 256 + i) * 16;
#pragma unroll
        for (int k = 0; k < 16; ++k) wn[k] = pn[k];
#pragma unroll
        for (int k = 0; k < 16; ++k) PIN4(wn[k]);
        WINIT( 0,  0,  1,  2,  3,  64, 65, 66, 67)
        WINIT( 1,  4,  5,  6,  7,  68, 69, 70, 71)
        WINIT( 2,  8,  9, 10, 11,  72, 73, 74, 75)
        WINIT( 3, 12, 13, 14, 15,  76, 77, 78, 79)
        WINIT( 4, 16, 17, 18, 19,  80, 81, 82, 83)
        WINIT( 5, 20, 21, 22, 23,  84, 85, 86, 87)
        WINIT( 6, 24, 25, 26, 27,  88, 89, 90, 91)
        WINIT( 7, 28, 29, 30, 31,  92, 93, 94, 95)
        WINIT( 8, 32, 33, 34, 35,  96, 97, 98, 99)
        WINIT( 9, 36, 37, 38, 39, 100,101,102,103)
        WINIT(10, 40, 41, 42, 43, 104,105,106,107)
        WINIT(11, 44, 45, 46, 47, 108,109,110,111)
        WINIT(12, 48, 49, 50, 51, 112,113,114,115)
        WINIT(13, 52, 53, 54, 55, 116,117,118,119)
        WINIT(14, 56, 57, 58, 59, 120,121,122,123)
        WINIT(15, 60, 61, 62, 63, 124,125,126,127)
    }
    float bhr = bhh[i], bhz = bhh[256 + i], bhn = bhh[512 + i];
    float h = first ? 0.f : hstate[(size_t)blk * 256 + i];

    ((char*)&hq8[0][0])[i] = (char)(int)rintf(h * 127.f);
    __syncthreads();

    const _Float16* xgp = xg + (size_t)d * CROWS * 768 + (size_t)b * 768 + i;
    float xr = (float)xgp[0], xz = (float)xgp[256], xn = (float)xgp[512];
    xgp += (size_t)64 * 768;
    _Float16* ep = encc + (size_t)b * 512 + d * 256 + i;

    int cur = 0;
    for (int t = 0; t < len; ++t) {
        // prefetch next step's xg (last iter reads past chunk -> inside ws, unused)
        float pxr = (float)xgp[0], pxz = (float)xgp[256], pxn = (float)xgp[512];
        xgp += (size_t)64 * 768;

        const uint4* hqp = (const uint4*)&hq8[cur][0];   // 16 b128 broadcasts
        int i0 = 0, i1 = 0, i2 = 0;
        KSTEP( 0,  0,  1,  2,  3,  64, 65, 66, 67)
        KSTEP( 1,  4,  5,  6,  7,  68, 69, 70, 71)
        KSTEP( 2,  8,  9, 10, 11,  72, 73, 74, 75)
        KSTEP( 3, 12, 13, 14, 15,  76, 77, 78, 79)
        KSTEP( 4, 16, 17, 18, 19,  80, 81, 82, 83)
        KSTEP( 5, 20, 21, 22, 23,  84, 85, 86, 87)
        KSTEP( 6, 24, 25, 26, 27,  88, 89, 90, 91)
        KSTEP( 7, 28, 29, 30, 31,  92, 93, 94, 95)
        KSTEP( 8, 32, 33, 34, 35,  96, 97, 98, 99)
        KSTEP( 9, 36, 37, 38, 39, 100,101,102,103)
        KSTEP(10, 40, 41, 42, 43, 104,105,106,107)
        KSTEP(11, 44, 45, 46, 47, 108,109,110,111)
        KSTEP(12, 48, 49, 50, 51, 112,113,114,115)
        KSTEP(13, 52, 53, 54, 55, 116,117,118,119)
        KSTEP(14, 56, 57, 58, 59, 120,121,122,123)
        KSTEP(15, 60, 61, 62, 63, 124,125,126,127)

        float hr = (float)i0 * INV8 + bhr;
        float hz = (float)i1 * INV8 + bhz;
        float hn = (float)i2 * INV8 + bhn;
        float rg = 1.f / (1.f + __expf(-(xr + hr)));
        float zg = 1.f / (1.f + __expf(-(xz + hz)));
        float xnr = xn + rg * hn;
        float nv = 1.f - 2.f / (__expf(2.f * xnr) + 1.f);   // tanh
        h = (1.f - zg) * nv + zg * h;

        int nxt = cur ^ 1;
        ((char*)&hq8[nxt][0])[i] = (char)(int)rintf(h * 127.f);
        ep[(size_t)t * 64 * 512] = (_Float16)h;             // stream enc (no dependency)
        __syncthreads();
        cur = nxt;
        xr = pxr; xz = pxz; xn = pxn;
    }
    hstate[(size_t)blk * 256 + i] = h;
}

// ---------------- clf: psum[t,b,c] = clf_w[c,:] . enc[t,b,:] (one wave per row) ----------------
__global__ __launch_bounds__(256)
void clf_kernel(const _Float16* __restrict__ encc, const float* __restrict__ clf_w,
                float* __restrict__ psum, int t0, int len) {
    int w = (blockIdx.x * 256 + threadIdx.x) >> 6;   // global wave index = tl*64+b
    int lane = threadIdx.x & 63;
    if (w >= len * 64) return;
    const _Float16* row = encc + (size_t)w * 512 + lane * 8;
    uint4 v = *(const uint4*)row;
    float4 c0a = *(const float4*)(clf_w + lane * 8);
    float4 c0b = *(const float4*)(clf_w + lane * 8 + 4);
    float4 c1a = *(const float4*)(clf_w + 512 + lane * 8);
    float4 c1b = *(const float4*)(clf_w + 512 + lane * 8 + 4);
    h2_t e0 = __builtin_bit_cast(h2_t, v.x), e1 = __builtin_bit_cast(h2_t, v.y);
    h2_t e2 = __builtin_bit_cast(h2_t, v.z), e3 = __builtin_bit_cast(h2_t, v.w);
    float s0 = c0a.x * (float)e0[0] + c0a.y * (float)e0[1] + c0a.z * (float)e1[0] + c0a.w * (float)e1[1]
             + c0b.x * (float)e2[0] + c0b.y * (float)e2[1] + c0b.z * (float)e3[0] + c0b.w * (float)e3[1];
    float s1 = c1a.x * (float)e0[0] + c1a.y * (float)e0[1] + c1a.z * (float)e1[0] + c1a.w * (float)e1[1]
             + c1b.x * (float)e2[0] + c1b.y * (float)e2[1] + c1b.z * (float)e3[0] + c1b.w * (float)e3[1];
#pragma unroll
    for (int off = 32; off; off >>= 1) {
        s0 += __shfl_xor(s0, off, 64);
        s1 += __shfl_xor(s1, off, 64);
    }
    if (lane == 0) {
        int tl = w >> 6, b = w & 63;
        psum[((size_t)(t0 + tl) * 64 + b) * 2 + 0] = s0;
        psum[((size_t)(t0 + tl) * 64 + b) * 2 + 1] = s1;
    }
}

// ---------------- final: sliding mean over W steps + clf bias ----------------
__global__ void final_kernel(const float* __restrict__ psum, const float* __restrict__ clf_b,
                             const int* __restrict__ win, float* __restrict__ out) {
    int idx = blockIdx.x * 256 + threadIdx.x;
    if (idx >= TOUT * 128) return;
    int c = idx & 1;
    int rem = idx >> 1;
    int b = rem & 63;
    int tau = rem >> 6;
    int W = win[0] - 5 + 1;   // 96
    float s = 0.f;
    for (int j = 0; j < W; ++j)
        s += psum[((size_t)(tau + j) * 64 + b) * 2 + c];
    out[idx] = s / (float)W + clf_b[c];
}

extern "C" void kernel_launch(void* const* d_in, const int* in_sizes, int n_in,
                              void* d_out, int out_size, void* d_ws, size_t ws_size,
                              hipStream_t stream) {
    const float* x      = (const float*)d_in[0];
    const float* conv_w = (const float*)d_in[1];
    const float* conv_b = (const float*)d_in[2];
    const float* w_ih_f = (const float*)d_in[3];
    const float* w_hh_f = (const float*)d_in[4];
    const float* b_ih_f = (const float*)d_in[5];
    const float* b_hh_f = (const float*)d_in[6];
    const float* w_ih_r = (const float*)d_in[7];
    const float* w_hh_r = (const float*)d_in[8];
    const float* b_ih_r = (const float*)d_in[9];
    const float* b_hh_r = (const float*)d_in[10];
    const float* clf_w  = (const float*)d_in[11];
    const float* clf_b  = (const float*)d_in[12];
    const int*   win    = (const int*)d_in[13];
    float* out = (float*)d_out;

    char* ws = (char*)d_ws;
    _Float16* seqc = (_Float16*)(ws + OFF_SEQC);
    _Float16* xg   = (_Float16*)(ws + OFF_XG);
    float*    wT   = (float*)(ws + OFF_WT);
    _Float16* wcat = (_Float16*)(ws + OFF_WCAT);
    float*    psum = (float*)(ws + OFF_PSUM);
    float*    hst  = (float*)(ws + OFF_HST);
    unsigned* wq   = (unsigned*)(ws + OFF_WQ);
    _Float16* encc = (_Float16*)(ws + OFF_ENC);

    int prep_elems = 400 * 256 + NN * 256 + 2 * 3 * 256 * 64;
    prep_kernel<<<(prep_elems + 255) / 256, 256, 0, stream>>>(
        conv_w, w_ih_f, w_ih_r, w_hh_f, w_hh_r, wT, wcat, wq);

    for (int c = 0; c < NCHK; ++c) {
        int t0  = c * TCH;
        int len = (c == NCHK - 1) ? (TC - t0) : TCH;   // 250 / last 246
        conv_kernel<<<dim3(4, 64), 256, 0, stream>>>(x, wT, conv_b, seqc, t0, len);
        proj_kernel<<<dim3(len * 64 / 128, 12), 256, 0, stream>>>(seqc, wcat, b_ih_f, b_ih_r, xg);
        scan_kernel<<<128, 256, 0, stream>>>(xg, (const uint4*)wq, b_hh_f, b_hh_r,
                                             hst, encc, t0, len, c == 0);
        clf_kernel<<<len * 16, 256, 0, stream>>>(encc, clf_w, psum, t0, len);
    }
    final_kernel<<<(TOUT * 128 + 255) / 256, 256, 0, stream>>>(psum, clf_b, win, out);
}

// Round 7
// 3196.914 us; speedup vs baseline: 1.2491x; 1.2491x over previous
//
#include <hip/hip_runtime.h>
#include <hip/hip_bf16.h>

// KWSNet: conv1d+relu -> 2x GRU (fwd-scan, two weight sets) -> sliding mean -> linear(2)
// B=64, M=80, T=2000, C=H=256, K=5; Tc=1996, W=96, Tout=1901, out (1901,1,64,2) fp32.
//
// Chunked pipeline (8 x <=250 steps): conv -> proj (fp16 MFMA) -> persistent GRU
// scan (3-way gate pipe-split + fused clf) -> final.
//
// R19: tier tally complete: L2 185us (R12), LDS 237us (R17), scratch 246us
// (R13/R16), AGPR-asm 379us (R18: volatile accvgpr_reads serialized + wn
// spilled). No single tier feeds 192KB/step. R17 calibration: step ~= 192 LDS
// b128 x 12cyc -> h-BROADCAST costs like distinct reads (768cyc/CU alone).
// Fix: split gates across the three independent pipes at 1/3 load each:
//   n -> 16 pinned-VGPR uint4 (R17-proven residency: 132 = 64+68, no spill)
//   r -> LDS lwr[16][256], 16 conflict-free b128/thr/step (768 cyc/CU)
//   z -> streamed from L2 in-loop, unpinned (R12-proven 108 B/cyc; 592 cyc)
//   h -> OFF the LDS pipe: 1 ds_read_b32 + 64 v_readlane -> SGPRs, sdot4 with
//        SGPR src1 (VOP3P: 1 SGPR legal); two 32-SGPR halves to cap pressure.
// Fused clf: butterfly + per-wave LDS partials -> psum2[d]; enc + clf_kernel
// deleted (16MB/chunk round-trip + 8 launches gone).
// Per-step/CU: VALU ~660, LDS ~850, L2 ~592 -> ~105-135us/chunk.
// Predict: scan 100-140us, VGPR ~132 no-scratch, SGPR ~70-100, WRITE ~0.3MB.
// Falsify: >=170us => pipe-split dead; check disasm for readlane/SGPR fold.

#define TT    2000
#define TC    1996
#define NB    64
#define MCH   80
#define NH    256
#define NN    1536           // 2 * 3H
#define TOUT  1901
#define TCH   250            // chunk length (last chunk = 246)
#define NCHK  8
#define CROWS (TCH * NB)     // 16000 rows per chunk

typedef _Float16 h2_t __attribute__((ext_vector_type(2)));
typedef _Float16 h8_t __attribute__((ext_vector_type(8)));
typedef float    f4_t __attribute__((ext_vector_type(4)));

#define WQSCALE 254.0f
#define INV8    (1.0f / (254.0f * 127.0f))

// ---------------- workspace layout (bytes), total ~62.2 MB ----------------
#define OFF_SEQC ((size_t)0)            // fp16 [CROWS][256]      = 8,192,000
#define OFF_XG   ((size_t)8192000)      // fp16 [2][CROWS][768]   = 49,152,000
#define OFF_WT   ((size_t)57344000)     // fp32 [400][256]        = 409,600
#define OFF_WCAT ((size_t)57753600)     // fp16 [1536][256]       = 786,432
#define OFF_PSUM ((size_t)58540032)     // (unused, kept for layout stability)
#define OFF_HST  ((size_t)59561984)     // fp32 [128][256]        = 131,072
#define OFF_WQ   ((size_t)59693056)     // u32  [2][3][256][64]   = 393,216  (int8 W_hh, all cols)
#define OFF_PS2  ((size_t)60086272)     // fp32 [2][TC][64][2]    = 2,043,904

// ---------------- prep: transpose conv_w, fp16 w_ih concat, int8-quantize W_hh ----------------
__global__ void prep_kernel(const float* __restrict__ conv_w,
                            const float* __restrict__ wihf,
                            const float* __restrict__ wihr,
                            const float* __restrict__ whhf,
                            const float* __restrict__ whhr,
                            float* __restrict__ wT,
                            _Float16* __restrict__ wcat,
                            unsigned* __restrict__ wq) {
    int idx = blockIdx.x * 256 + threadIdx.x;
    if (idx < 400 * 256) {
        int c = idx & 255, mk = idx >> 8;
        wT[idx] = conv_w[c * 400 + mk];
    }
    int i2 = idx - 400 * 256;
    if (i2 >= 0 && i2 < NN * 256) {
        int k = i2 & 255, n = i2 >> 8;
        float v = (n < 768) ? wihf[n * 256 + k] : wihr[(n - 768) * 256 + k];
        wcat[i2] = (_Float16)v;
    }
    int i4 = idx - (400 * 256 + NN * 256);
    if (i4 >= 0 && i4 < 2 * 3 * 256 * 64) {
        // element (d,g,r,j): uint packs cols 4j..4j+3 of row g*256+r of whh_d
        int r  = i4 & 255;
        int j  = (i4 >> 8) & 63;
        int dg = i4 >> 14;               // 0..5 = d*3+g
        const float* whh = (dg >= 3) ? whhr : whhf;
        int g = (dg >= 3) ? dg - 3 : dg;
        const float* wp = whh + (size_t)(g * 256 + r) * 256 + 4 * j;
        unsigned v = 0;
#pragma unroll
        for (int kk = 0; kk < 4; ++kk) {
            float q = rintf(wp[kk] * WQSCALE);
            q = fminf(fmaxf(q, -127.f), 127.f);
            v |= ((unsigned)((int)q & 0xFF)) << (8 * kk);
        }
        wq[((size_t)dg * 256 + r) * 64 + j] = v;
    }
}

// ---------------- conv1d(valid,K=5)+bias+relu -> seqc fp16 [t_local*64+b][c] ----------------
__global__ __launch_bounds__(256, 2)
void conv_kernel(const float* __restrict__ x, const float* __restrict__ wT,
                 const float* __restrict__ conv_b, _Float16* __restrict__ seqc,
                 int t_base, int t_len) {
    __shared__ float xs[MCH][68];
    int tile = blockIdx.x;           // 0..3
    int b    = blockIdx.y;           // 0..63
    int tid  = threadIdx.x;
    for (int idx = tid; idx < MCH * 68; idx += 256) {
        int m = idx / 68, i = idx - m * 68;
        int tt = t_base + tile * 64 + i;
        xs[m][i] = (tt < TT) ? x[(size_t)b * (MCH * TT) + m * TT + tt] : 0.f;
    }
    __syncthreads();
    int lane = tid & 63, tg = tid >> 6;   // wave tg: t-range [tg*16, tg*16+16)
    float acc[4][16];
#pragma unroll
    for (int cq = 0; cq < 4; ++cq)
#pragma unroll
        for (int t = 0; t < 16; ++t) acc[cq][t] = 0.f;

    for (int m = 0; m < MCH; ++m) {
        float xr_[20];
#pragma unroll
        for (int q = 0; q < 5; ++q) {
            float4 v = *(const float4*)&xs[m][tg * 16 + q * 4];
            xr_[q * 4 + 0] = v.x; xr_[q * 4 + 1] = v.y;
            xr_[q * 4 + 2] = v.z; xr_[q * 4 + 3] = v.w;
        }
#pragma unroll
        for (int cq = 0; cq < 4; ++cq) {
            int c = lane + cq * 64;
            const float* wp = wT + (size_t)(m * 5) * 256 + c;
            float w0_ = wp[0], w1_ = wp[256], w2_ = wp[512], w3_ = wp[768], w4_ = wp[1024];
#pragma unroll
            for (int t = 0; t < 16; ++t)
                acc[cq][t] += w0_ * xr_[t] + w1_ * xr_[t + 1] + w2_ * xr_[t + 2]
                            + w3_ * xr_[t + 3] + w4_ * xr_[t + 4];
        }
    }
#pragma unroll
    for (int cq = 0; cq < 4; ++cq) {
        int c = lane + cq * 64;
        float cb = conv_b[c];
        for (int t = 0; t < 16; ++t) {
            int tl = tile * 64 + tg * 16 + t;     // t within chunk
            if (tl < t_len) {
                float v = acc[cq][t] + cb;
                v = v > 0.f ? v : 0.f;
                seqc[((size_t)tl * 64 + b) * 256 + c] = (_Float16)v;
            }
        }
    }
}

// ---------------- proj: xg[d][row][j] = seqc @ w_ih^T + b_ih (fp16 MFMA 16x16x32) ----------------
__global__ __launch_bounds__(256, 2)
void proj_kernel(const _Float16* __restrict__ seqc, const _Float16* __restrict__ wcat,
                 const float* __restrict__ bihf, const float* __restrict__ bihr,
                 _Float16* __restrict__ xg) {
    __shared__ __align__(16) _Float16 As[128][72];
    __shared__ __align__(16) _Float16 Bs[128][72];
    int row0 = blockIdx.x * 128;     // up to 125 tiles
    int n0   = blockIdx.y * 128;     // 12 tiles
    int tid  = threadIdx.x;
    int lane = tid & 63, wv = tid >> 6;
    int wr = wv >> 1, wc = wv & 1;                 // 2x2 waves of 64x64
    int fm = lane & 15, fq = lane >> 4;            // fragment index, quad
    f4_t acc[4][4];
#pragma unroll
    for (int mt = 0; mt < 4; ++mt)
#pragma unroll
        for (int nt = 0; nt < 4; ++nt) acc[mt][nt] = (f4_t){0.f, 0.f, 0.f, 0.f};

    int r = tid >> 1, part = tid & 1;
    for (int kc = 0; kc < 4; ++kc) {
        const uint4* srcA = (const uint4*)&seqc[(size_t)(row0 + r) * 256 + kc * 64 + part * 32];
        const uint4* srcB = (const uint4*)&wcat[(size_t)(n0 + r) * 256 + kc * 64 + part * 32];
        uint4* dstA = (uint4*)&As[r][part * 32];
        uint4* dstB = (uint4*)&Bs[r][part * 32];
        dstA[0] = srcA[0]; dstA[1] = srcA[1]; dstA[2] = srcA[2]; dstA[3] = srcA[3];
        dstB[0] = srcB[0]; dstB[1] = srcB[1]; dstB[2] = srcB[2]; dstB[3] = srcB[3];
        __syncthreads();
#pragma unroll
        for (int ks = 0; ks < 64; ks += 32) {
            h8_t af[4], bf[4];
#pragma unroll
            for (int mt = 0; mt < 4; ++mt)
                af[mt] = *(const h8_t*)&As[wr * 64 + mt * 16 + fm][ks + fq * 8];
#pragma unroll
            for (int nt = 0; nt < 4; ++nt)
                bf[nt] = *(const h8_t*)&Bs[wc * 64 + nt * 16 + fm][ks + fq * 8];
#pragma unroll
            for (int mt = 0; mt < 4; ++mt)
#pragma unroll
                for (int nt = 0; nt < 4; ++nt)
                    acc[mt][nt] = __builtin_amdgcn_mfma_f32_16x16x32_f16(
                        af[mt], bf[nt], acc[mt][nt], 0, 0, 0);
        }
        __syncthreads();
    }
    // epilogue: C col = lane&15 (n-dim), row = (lane>>4)*4 + reg (m-dim)
#pragma unroll
    for (int nt = 0; nt < 4; ++nt) {
        int col = n0 + wc * 64 + nt * 16 + fm;
        int d = (col < 768) ? 0 : 1;
        int j = col - d * 768;
        float bias = d ? bihr[j] : bihf[j];
        size_t obase = (size_t)d * CROWS * 768 + j;
#pragma unroll
        for (int mt = 0; mt < 4; ++mt) {
            int row = row0 + wr * 64 + mt * 16 + fq * 4;
#pragma unroll
            for (int rr = 0; rr < 4; ++rr)
                xg[obase + (size_t)(row + rr) * 768] = (_Float16)(acc[mt][nt][rr] + bias);
        }
    }
}

// ---------------- persistent GRU scan chunk: 1 block (256 thr) per (direction, batch) ----------------
// Gate n: 16 pinned-VGPR uint4. Gate r: LDS (conflict-free b128). Gate z: L2
// stream (unpinned in-loop loads). h: 1 ds_read_b32 + 64 v_readlane -> SGPRs.
// clf fused: butterfly + per-wave LDS partials -> psum2[d][t][b][2].
#define SD4(a, b, c) __builtin_amdgcn_sdot4((int)(a), (int)(b), (c), false)
#define PIN4(v) asm volatile("" : "+v"((v).x), "+v"((v).y), "+v"((v).z), "+v"((v).w))

__global__ __launch_bounds__(256)
void scan_kernel(const _Float16* __restrict__ xg, const uint4* __restrict__ wq,
                 const float* __restrict__ bhhf, const float* __restrict__ bhhr,
                 const float* __restrict__ clfw,
                 float* __restrict__ hstate, float* __restrict__ psum2,
                 int t0, int len, int first) {
    int blk = blockIdx.x;
    int d = blk >> 6, b = blk & 63;
    int i = threadIdx.x;
    int lane = i & 63, wv = i >> 6;
    const float* bhh = d ? bhhr : bhhf;

    __shared__ __align__(16) uint4 lwr[16][256];    // gate r, transposed: 64 KB
    __shared__ __align__(16) unsigned hq8[2][64];   // int8 h, double-buffered
    __shared__ float cwp[2][4][2];                  // clf per-wave partials, dbuf

    // stage: r -> LDS; n -> pinned VGPRs; z stays in L2 (streamed per step)
    uint4 wn[16];
    const uint4* pz = wq + ((size_t)(d * 3 + 1) * 256 + i) * 16;
    {
        const uint4* pr = wq + ((size_t)(d * 3 + 0) * 256 + i) * 16;
        const uint4* pn = wq + ((size_t)(d * 3 + 2) * 256 + i) * 16;
#pragma unroll
        for (int k = 0; k < 16; ++k) { lwr[k][i] = pr[k]; wn[k] = pn[k]; }
#pragma unroll
        for (int k = 0; k < 16; ++k) PIN4(wn[k]);
    }
    float bhr = bhh[i], bhz = bhh[256 + i], bhn = bhh[512 + i];
    float cw0 = clfw[d * 256 + i], cw1 = clfw[512 + d * 256 + i];
    float h = first ? 0.f : hstate[(size_t)blk * 256 + i];

    ((char*)&hq8[0][0])[i] = (char)(int)rintf(h * 127.f);
    __syncthreads();

    const _Float16* xgp = xg + (size_t)d * CROWS * 768 + (size_t)b * 768 + i;
    float xr = (float)xgp[0], xz = (float)xgp[256], xn = (float)xgp[512];
    xgp += (size_t)64 * 768;

    int cur = 0;
    for (int t = 0; t < len; ++t) {
        // prefetch next step's xg (last iter reads past chunk -> inside ws, unused)
        float pxr = (float)xgp[0], pxz = (float)xgp[256], pxn = (float)xgp[512];
        xgp += (size_t)64 * 768;

        // h gather: lane l holds dword l; readlane -> SGPRs (two 32-reg halves)
        unsigned hv = hq8[cur][lane];
        int i0 = 0, i1 = 0, i2 = 0;
        unsigned hs[32];
#pragma unroll
        for (int half = 0; half < 2; ++half) {
#pragma unroll
            for (int l = 0; l < 32; ++l)
                hs[l] = (unsigned)__builtin_amdgcn_readlane((int)hv, half * 32 + l);
#pragma unroll
            for (int k = 0; k < 8; ++k) {
                int kk = half * 8 + k;
                uint4 wz_ = pz[kk];          // L2 stream, unpinned
                uint4 wr_ = lwr[kk][i];      // LDS, conflict-free b128
                i0 = SD4(wr_.x, hs[4*k+0], i0); i0 = SD4(wr_.y, hs[4*k+1], i0);
                i0 = SD4(wr_.z, hs[4*k+2], i0); i0 = SD4(wr_.w, hs[4*k+3], i0);
                i2 = SD4(wn[kk].x, hs[4*k+0], i2); i2 = SD4(wn[kk].y, hs[4*k+1], i2);
                i2 = SD4(wn[kk].z, hs[4*k+2], i2); i2 = SD4(wn[kk].w, hs[4*k+3], i2);
                i1 = SD4(wz_.x, hs[4*k+0], i1); i1 = SD4(wz_.y, hs[4*k+1], i1);
                i1 = SD4(wz_.z, hs[4*k+2], i1); i1 = SD4(wz_.w, hs[4*k+3], i1);
            }
        }

        float hr = (float)i0 * INV8 + bhr;
        float hz = (float)i1 * INV8 + bhz;
        float hn = (float)i2 * INV8 + bhn;
        float rg = 1.f / (1.f + __expf(-(xr + hr)));
        float zg = 1.f / (1.f + __expf(-(xz + hz)));
        float xnr = xn + rg * hn;
        float nv = 1.f - 2.f / (__expf(2.f * xnr) + 1.f);   // tanh
        h = (1.f - zg) * nv + zg * h;

        // fused clf partial: butterfly within wave, partials to LDS
        float s0 = cw0 * h, s1 = cw1 * h;
#pragma unroll
        for (int off = 32; off; off >>= 1) {
            s0 += __shfl_xor(s0, off, 64);
            s1 += __shfl_xor(s1, off, 64);
        }
        int nxt = cur ^ 1;
        ((char*)&hq8[nxt][0])[i] = (char)(int)rintf(h * 127.f);
        if (lane == 0) { cwp[nxt][wv][0] = s0; cwp[nxt][wv][1] = s1; }
        __syncthreads();
        if (i == 0) {
            float a0 = cwp[nxt][0][0] + cwp[nxt][1][0] + cwp[nxt][2][0] + cwp[nxt][3][0];
            float a1 = cwp[nxt][0][1] + cwp[nxt][1][1] + cwp[nxt][2][1] + cwp[nxt][3][1];
            float* pp = psum2 + (((size_t)d * TC + (t0 + t)) * 64 + b) * 2;
            pp[0] = a0; pp[1] = a1;
        }
        cur = nxt;
        xr = pxr; xz = pxz; xn = pxn;
    }
    hstate[(size_t)blk * 256 + i] = h;
}

// ---------------- final: sliding mean over W steps (both direction halves) + clf bias ----------------
__global__ void final_kernel(const float* __restrict__ psum2, const float* __restrict__ clf_b,
                             const int* __restrict__ win, float* __restrict__ out) {
    int idx = blockIdx.x * 256 + threadIdx.x;
    if (idx >= TOUT * 128) return;
    int c = idx & 1;
    int rem = idx >> 1;
    int b = rem & 63;
    int tau = rem >> 6;
    int W = win[0] - 5 + 1;   // 96
    const float* p0 = psum2;
    const float* p1 = psum2 + (size_t)TC * 64 * 2;
    float s = 0.f;
    for (int j = 0; j < W; ++j) {
        size_t o = ((size_t)(tau + j) * 64 + b) * 2 + c;
        s += p0[o] + p1[o];
    }
    out[idx] = s / (float)W + clf_b[c];
}

extern "C" void kernel_launch(void* const* d_in, const int* in_sizes, int n_in,
                              void* d_out, int out_size, void* d_ws, size_t ws_size,
                              hipStream_t stream) {
    const float* x      = (const float*)d_in[0];
    const float* conv_w = (const float*)d_in[1];
    const float* conv_b = (const float*)d_in[2];
    const float* w_ih_f = (const float*)d_in[3];
    const float* w_hh_f = (const float*)d_in[4];
    const float* b_ih_f = (const float*)d_in[5];
    const float* b_hh_f = (const float*)d_in[6];
    const float* w_ih_r = (const float*)d_in[7];
    const float* w_hh_r = (const float*)d_in[8];
    const float* b_ih_r = (const float*)d_in[9];
    const float* b_hh_r = (const float*)d_in[10];
    const float* clf_w  = (const float*)d_in[11];
    const float* clf_b  = (const float*)d_in[12];
    const int*   win    = (const int*)d_in[13];
    float* out = (float*)d_out;

    char* ws = (char*)d_ws;
    _Float16* seqc = (_Float16*)(ws + OFF_SEQC);
    _Float16* xg   = (_Float16*)(ws + OFF_XG);
    float*    wT   = (float*)(ws + OFF_WT);
    _Float16* wcat = (_Float16*)(ws + OFF_WCAT);
    float*    hst  = (float*)(ws + OFF_HST);
    unsigned* wq   = (unsigned*)(ws + OFF_WQ);
    float*    ps2  = (float*)(ws + OFF_PS2);

    int prep_elems = 400 * 256 + NN * 256 + 2 * 3 * 256 * 64;
    prep_kernel<<<(prep_elems + 255) / 256, 256, 0, stream>>>(
        conv_w, w_ih_f, w_ih_r, w_hh_f, w_hh_r, wT, wcat, wq);

    for (int c = 0; c < NCHK; ++c) {
        int t0  = c * TCH;
        int len = (c == NCHK - 1) ? (TC - t0) : TCH;   // 250 / last 246
        conv_kernel<<<dim3(4, 64), 256, 0, stream>>>(x, wT, conv_b, seqc, t0, len);
        proj_kernel<<<dim3(len * 64 / 128, 12), 256, 0, stream>>>(seqc, wcat, b_ih_f, b_ih_r, xg);
        scan_kernel<<<128, 256, 0, stream>>>(xg, (const uint4*)wq, b_hh_f, b_hh_r, clf_w,
                                             hst, ps2, t0, len, c == 0);
    }
    final_kernel<<<(TOUT * 128 + 255) / 256, 256, 0, stream>>>(ps2, clf_b, win, out);
}

// Round 8
// 2366.532 us; speedup vs baseline: 1.6873x; 1.3509x over previous
//
#include <hip/hip_runtime.h>
#include <hip/hip_bf16.h>

// KWSNet: conv1d+relu -> 2x GRU (fwd-scan, two weight sets) -> sliding mean -> linear(2)
// B=64, M=80, T=2000, C=H=256, K=5; Tc=1996, W=96, Tout=1901, out (1901,1,64,2) fp32.
//
// R20: scan declared structurally floored at ~185us/250steps (tier tally across
// R12-R19: L2 185 / LDS 237 / scratch 246 / AGPR 379 / hybrid 279; compute
// floor 384cyc/step vs delivery floor ~1600cyc/step; all batching/tiling
// rearrangements re-derive the same per-XCD L2 bound). Attack the OTHER ~1000us:
// conv/proj/clf ran serially while scan uses only 128/256 CUs. Events are
// forbidden (graph capture), so overlap via FAT KERNEL: one launch per chunk
// hosts 3 independent roles: scan_k (blocks 0..127) || proj_{k+1} || conv_{k+2}.
// conv->proj dependency offset by 2 chunks => satisfied by launch serialization;
// seqc/xg parity-double-buffered; TCH=126 (16 chunks) so 2x xg fits proven ws.
// Scan role = EXACT R12 inner loop (best measured) + R19's proven fused clf
// (removes 8 clf launches + enc roundtrip). Predict: 16 fat dispatches ~95-115us,
// total 2475 -> ~1750-1950us. Falsify: fat >=150us => overlap failed.

#define TT    2000
#define TC    1996
#define NB    64
#define MCH   80
#define NN    1536           // 2 * 3H
#define TOUT  1901
#define TCH   126            // chunk length (last chunk = 106)
#define NCHK  16
#define CROWS (TCH * NB)     // 8064 rows per chunk parity

typedef _Float16 h8_t __attribute__((ext_vector_type(8)));
typedef float    f4_t __attribute__((ext_vector_type(4)));

#define WQSCALE 254.0f
#define INV8    (1.0f / (254.0f * 127.0f))

// ---------------- workspace layout (bytes), total ~61.6 MB (proven ws >= 76.5 MB) ----------------
#define OFF_SEQC ((size_t)0)            // fp16 [2 parity][8064][256]      = 8,257,536
#define OFF_XG   ((size_t)8257536)      // fp16 [2 parity][2 dir][8064][768] = 49,545,216
#define OFF_WT   ((size_t)57802752)     // fp32 [400][256]                 = 409,600
#define OFF_WCAT ((size_t)58212352)     // fp16 [1536][256]                = 786,432
#define OFF_HST  ((size_t)58998784)     // fp32 [128][256]                 = 131,072
#define OFF_WQ   ((size_t)59129856)     // u32  [2][3][256][64]            = 393,216
#define OFF_PS2  ((size_t)59523072)     // fp32 [2][TC][64][2]             = 2,043,904 -> 61,566,976

// ---------------- prep: transpose conv_w, fp16 w_ih concat, int8-quantize W_hh ----------------
__global__ void prep_kernel(const float* __restrict__ conv_w,
                            const float* __restrict__ wihf,
                            const float* __restrict__ wihr,
                            const float* __restrict__ whhf,
                            const float* __restrict__ whhr,
                            float* __restrict__ wT,
                            _Float16* __restrict__ wcat,
                            unsigned* __restrict__ wq) {
    int idx = blockIdx.x * 256 + threadIdx.x;
    if (idx < 400 * 256) {
        int c = idx & 255, mk = idx >> 8;
        wT[idx] = conv_w[c * 400 + mk];
    }
    int i2 = idx - 400 * 256;
    if (i2 >= 0 && i2 < NN * 256) {
        int k = i2 & 255, n = i2 >> 8;
        float v = (n < 768) ? wihf[n * 256 + k] : wihr[(n - 768) * 256 + k];
        wcat[i2] = (_Float16)v;
    }
    int i4 = idx - (400 * 256 + NN * 256);
    if (i4 >= 0 && i4 < 2 * 3 * 256 * 64) {
        int r  = i4 & 255;
        int j  = (i4 >> 8) & 63;
        int dg = i4 >> 14;               // 0..5 = d*3+g
        const float* whh = (dg >= 3) ? whhr : whhf;
        int g = (dg >= 3) ? dg - 3 : dg;
        const float* wp = whh + (size_t)(g * 256 + r) * 256 + 4 * j;
        unsigned v = 0;
#pragma unroll
        for (int kk = 0; kk < 4; ++kk) {
            float q = rintf(wp[kk] * WQSCALE);
            q = fminf(fmaxf(q, -127.f), 127.f);
            v |= ((unsigned)((int)q & 0xFF)) << (8 * kk);
        }
        wq[((size_t)dg * 256 + r) * 64 + j] = v;
    }
}

// ---------------- fat kernel: scan_k || proj_{k+1} || conv_{k+2} ----------------
#define SD4(a, b, c) __builtin_amdgcn_sdot4((int)(a), (int)(b), (c), false)

__global__ __launch_bounds__(256)
void fat_kernel(
    // scan role (nscan blocks)
    int nscan, const _Float16* __restrict__ xg_s, const uint4* __restrict__ wq,
    const float* __restrict__ bhhf, const float* __restrict__ bhhr,
    const float* __restrict__ clfw, float* __restrict__ hstate,
    float* __restrict__ psum2, int t0s, int lens, int first,
    // proj role (nproj blocks)
    int nproj, const _Float16* __restrict__ seqc_p, const _Float16* __restrict__ wcat,
    const float* __restrict__ bihf, const float* __restrict__ bihr,
    _Float16* __restrict__ xg_p,
    // conv role (nconv blocks)
    int nconv, const float* __restrict__ x, const float* __restrict__ wT,
    const float* __restrict__ conv_b, _Float16* __restrict__ seqc_c,
    int t0c, int lenc)
{
    __shared__ __align__(16) char smem[36864];   // proj As+Bs = max role demand
    int bid = blockIdx.x;
    int tid = threadIdx.x;

    if (bid < nscan) {
        // ======== persistent GRU scan chunk (R12 inner loop + fused clf) ========
        int d = bid >> 6, b = bid & 63;
        int i = tid, lane = tid & 63, wv = tid >> 6;
        const float* bhh = d ? bhhr : bhhf;
        unsigned (*hq8)[64]  = (unsigned(*)[64])smem;       // [2][64] int8 h dbuf
        float (*cwp)[4][2]   = (float(*)[4][2])(smem + 512); // [2][4][2] clf partials

        // int8 weights, rows {i, i+256, i+512}: UNPINNED (R12 behavior: compiler
        // streams from L2 at ~108 B/cyc/CU -- the proven-best delivery tier)
        uint4 wa[16], wb[16], wc[16];
        {
            const uint4* pa = wq + ((size_t)(d * 3 + 0) * 256 + i) * 16;
            const uint4* pb = wq + ((size_t)(d * 3 + 1) * 256 + i) * 16;
            const uint4* pc = wq + ((size_t)(d * 3 + 2) * 256 + i) * 16;
#pragma unroll
            for (int k = 0; k < 16; ++k) { wa[k] = pa[k]; wb[k] = pb[k]; wc[k] = pc[k]; }
        }
        float bhr = bhh[i], bhz = bhh[256 + i], bhn = bhh[512 + i];
        float cw0 = clfw[d * 256 + i], cw1 = clfw[512 + d * 256 + i];
        float h = first ? 0.f : hstate[(size_t)bid * 256 + i];

        ((char*)&hq8[0][0])[i] = (char)(int)rintf(h * 127.f);
        __syncthreads();

        const _Float16* xgp = xg_s + (size_t)d * CROWS * 768 + (size_t)b * 768 + i;
        float xr = (float)xgp[0], xz = (float)xgp[256], xn = (float)xgp[512];
        xgp += (size_t)64 * 768;

        int cur = 0;
        for (int t = 0; t < lens; ++t) {
            // prefetch next step's xg (last iter reads past chunk -> inside ws, unused)
            float pxr = (float)xgp[0], pxz = (float)xgp[256], pxn = (float)xgp[512];
            xgp += (size_t)64 * 768;

            const uint4* hqp = (const uint4*)&hq8[cur][0];   // 16 b128 broadcasts
            int i0 = 0, i1 = 0, i2 = 0;
#pragma unroll
            for (int k = 0; k < 16; ++k) {
                uint4 hv = hqp[k];
                i0 = SD4(wa[k].x, hv.x, i0); i0 = SD4(wa[k].y, hv.y, i0);
                i0 = SD4(wa[k].z, hv.z, i0); i0 = SD4(wa[k].w, hv.w, i0);
                i1 = SD4(wb[k].x, hv.x, i1); i1 = SD4(wb[k].y, hv.y, i1);
                i1 = SD4(wb[k].z, hv.z, i1); i1 = SD4(wb[k].w, hv.w, i1);
                i2 = SD4(wc[k].x, hv.x, i2); i2 = SD4(wc[k].y, hv.y, i2);
                i2 = SD4(wc[k].z, hv.z, i2); i2 = SD4(wc[k].w, hv.w, i2);
            }

            float hr = (float)i0 * INV8 + bhr;
            float hz = (float)i1 * INV8 + bhz;
            float hn = (float)i2 * INV8 + bhn;
            float rg = 1.f / (1.f + __expf(-(xr + hr)));
            float zg = 1.f / (1.f + __expf(-(xz + hz)));
            float xnr = xn + rg * hn;
            float nv = 1.f - 2.f / (__expf(2.f * xnr) + 1.f);   // tanh
            h = (1.f - zg) * nv + zg * h;

            // fused clf partial: butterfly within wave, partials via LDS
            float s0 = cw0 * h, s1 = cw1 * h;
#pragma unroll
            for (int off = 32; off; off >>= 1) {
                s0 += __shfl_xor(s0, off, 64);
                s1 += __shfl_xor(s1, off, 64);
            }
            int nxt = cur ^ 1;
            ((char*)&hq8[nxt][0])[i] = (char)(int)rintf(h * 127.f);
            if (lane == 0) { cwp[nxt][wv][0] = s0; cwp[nxt][wv][1] = s1; }
            __syncthreads();
            if (i == 0) {
                float a0 = cwp[nxt][0][0] + cwp[nxt][1][0] + cwp[nxt][2][0] + cwp[nxt][3][0];
                float a1 = cwp[nxt][0][1] + cwp[nxt][1][1] + cwp[nxt][2][1] + cwp[nxt][3][1];
                float* pp = psum2 + (((size_t)d * TC + (t0s + t)) * 64 + b) * 2;
                pp[0] = a0; pp[1] = a1;
            }
            cur = nxt;
            xr = pxr; xz = pxz; xn = pxn;
        }
        hstate[(size_t)bid * 256 + i] = h;

    } else if (bid < nscan + nproj) {
        // ======== proj: xg[d][row][j] = seqc @ w_ih^T + b_ih (fp16 MFMA) ========
        int pb = bid - nscan;
        int row0 = (pb / 12) * 128;
        int n0   = (pb % 12) * 128;
        _Float16 (*As)[72] = (_Float16(*)[72])smem;
        _Float16 (*Bs)[72] = (_Float16(*)[72])(smem + 18432);
        int lane = tid & 63, wv = tid >> 6;
        int wr = wv >> 1, wcn = wv & 1;                // 2x2 waves of 64x64
        int fm = lane & 15, fq = lane >> 4;
        f4_t acc[4][4];
#pragma unroll
        for (int mt = 0; mt < 4; ++mt)
#pragma unroll
            for (int nt = 0; nt < 4; ++nt) acc[mt][nt] = (f4_t){0.f, 0.f, 0.f, 0.f};

        int r = tid >> 1, part = tid & 1;
        for (int kc = 0; kc < 4; ++kc) {
            const uint4* srcA = (const uint4*)&seqc_p[(size_t)(row0 + r) * 256 + kc * 64 + part * 32];
            const uint4* srcB = (const uint4*)&wcat[(size_t)(n0 + r) * 256 + kc * 64 + part * 32];
            uint4* dstA = (uint4*)&As[r][part * 32];
            uint4* dstB = (uint4*)&Bs[r][part * 32];
            dstA[0] = srcA[0]; dstA[1] = srcA[1]; dstA[2] = srcA[2]; dstA[3] = srcA[3];
            dstB[0] = srcB[0]; dstB[1] = srcB[1]; dstB[2] = srcB[2]; dstB[3] = srcB[3];
            __syncthreads();
#pragma unroll
            for (int ks = 0; ks < 64; ks += 32) {
                h8_t af[4], bf[4];
#pragma unroll
                for (int mt = 0; mt < 4; ++mt)
                    af[mt] = *(const h8_t*)&As[wr * 64 + mt * 16 + fm][ks + fq * 8];
#pragma unroll
                for (int nt = 0; nt < 4; ++nt)
                    bf[nt] = *(const h8_t*)&Bs[wcn * 64 + nt * 16 + fm][ks + fq * 8];
#pragma unroll
                for (int mt = 0; mt < 4; ++mt)
#pragma unroll
                    for (int nt = 0; nt < 4; ++nt)
                        acc[mt][nt] = __builtin_amdgcn_mfma_f32_16x16x32_f16(
                            af[mt], bf[nt], acc[mt][nt], 0, 0, 0);
            }
            __syncthreads();
        }
#pragma unroll
        for (int nt = 0; nt < 4; ++nt) {
            int col = n0 + wcn * 64 + nt * 16 + fm;
            int d = (col < 768) ? 0 : 1;
            int j = col - d * 768;
            float bias = d ? bihr[j] : bihf[j];
            size_t obase = (size_t)d * CROWS * 768 + j;
#pragma unroll
            for (int mt = 0; mt < 4; ++mt) {
                int row = row0 + wr * 64 + mt * 16 + fq * 4;
#pragma unroll
                for (int rr = 0; rr < 4; ++rr)
                    xg_p[obase + (size_t)(row + rr) * 768] = (_Float16)(acc[mt][nt][rr] + bias);
            }
        }

    } else {
        // ======== conv1d(valid,K=5)+bias+relu -> seqc_c ========
        int cb = bid - nscan - nproj;
        int tile = cb >> 6;              // 0..1 (covers 128 t >= TCH)
        int b    = cb & 63;
        float (*xs)[68] = (float(*)[68])smem;
        for (int idx = tid; idx < MCH * 68; idx += 256) {
            int m = idx / 68, ii = idx - m * 68;
            int tt = t0c + tile * 64 + ii;
            xs[m][ii] = (tt < TT) ? x[(size_t)b * (MCH * TT) + m * TT + tt] : 0.f;
        }
        __syncthreads();
        int lane = tid & 63, tg = tid >> 6;
        float acc[4][16];
#pragma unroll
        for (int cq = 0; cq < 4; ++cq)
#pragma unroll
            for (int t = 0; t < 16; ++t) acc[cq][t] = 0.f;

        for (int m = 0; m < MCH; ++m) {
            float xr_[20];
#pragma unroll
            for (int q = 0; q < 5; ++q) {
                float4 v = *(const float4*)&xs[m][tg * 16 + q * 4];
                xr_[q * 4 + 0] = v.x; xr_[q * 4 + 1] = v.y;
                xr_[q * 4 + 2] = v.z; xr_[q * 4 + 3] = v.w;
            }
#pragma unroll
            for (int cq = 0; cq < 4; ++cq) {
                int c = lane + cq * 64;
                const float* wp = wT + (size_t)(m * 5) * 256 + c;
                float w0_ = wp[0], w1_ = wp[256], w2_ = wp[512], w3_ = wp[768], w4_ = wp[1024];
#pragma unroll
                for (int t = 0; t < 16; ++t)
                    acc[cq][t] += w0_ * xr_[t] + w1_ * xr_[t + 1] + w2_ * xr_[t + 2]
                                + w3_ * xr_[t + 3] + w4_ * xr_[t + 4];
            }
        }
#pragma unroll
        for (int cq = 0; cq < 4; ++cq) {
            int c = lane + cq * 64;
            float cb_ = conv_b[c];
            for (int t = 0; t < 16; ++t) {
                int tl = tile * 64 + tg * 16 + t;
                if (tl < lenc) {
                    float v = acc[cq][t] + cb_;
                    v = v > 0.f ? v : 0.f;
                    seqc_c[((size_t)tl * 64 + b) * 256 + c] = (_Float16)v;
                }
            }
        }
    }
}

// ---------------- final: sliding mean over W steps (both dirs) + clf bias ----------------
__global__ void final_kernel(const float* __restrict__ psum2, const float* __restrict__ clf_b,
                             const int* __restrict__ win, float* __restrict__ out) {
    int idx = blockIdx.x * 256 + threadIdx.x;
    if (idx >= TOUT * 128) return;
    int c = idx & 1;
    int rem = idx >> 1;
    int b = rem & 63;
    int tau = rem >> 6;
    int W = win[0] - 5 + 1;   // 96
    const float* p0 = psum2;
    const float* p1 = psum2 + (size_t)TC * 64 * 2;
    float s = 0.f;
    for (int j = 0; j < W; ++j) {
        size_t o = ((size_t)(tau + j) * 64 + b) * 2 + c;
        s += p0[o] + p1[o];
    }
    out[idx] = s / (float)W + clf_b[c];
}

extern "C" void kernel_launch(void* const* d_in, const int* in_sizes, int n_in,
                              void* d_out, int out_size, void* d_ws, size_t ws_size,
                              hipStream_t stream) {
    const float* x      = (const float*)d_in[0];
    const float* conv_w = (const float*)d_in[1];
    const float* conv_b = (const float*)d_in[2];
    const float* w_ih_f = (const float*)d_in[3];
    const float* w_hh_f = (const float*)d_in[4];
    const float* b_ih_f = (const float*)d_in[5];
    const float* b_hh_f = (const float*)d_in[6];
    const float* w_ih_r = (const float*)d_in[7];
    const float* w_hh_r = (const float*)d_in[8];
    const float* b_ih_r = (const float*)d_in[9];
    const float* b_hh_r = (const float*)d_in[10];
    const float* clf_w  = (const float*)d_in[11];
    const float* clf_b  = (const float*)d_in[12];
    const int*   win    = (const int*)d_in[13];
    float* out = (float*)d_out;

    char* ws = (char*)d_ws;
    _Float16* seqc = (_Float16*)(ws + OFF_SEQC);
    _Float16* xg   = (_Float16*)(ws + OFF_XG);
    float*    wT   = (float*)(ws + OFF_WT);
    _Float16* wcat = (_Float16*)(ws + OFF_WCAT);
    float*    hst  = (float*)(ws + OFF_HST);
    const uint4* wqp = (const uint4*)(ws + OFF_WQ);
    unsigned* wq   = (unsigned*)(ws + OFF_WQ);
    float*    ps2  = (float*)(ws + OFF_PS2);

    const size_t XGP = (size_t)2 * CROWS * 768;   // xg elements per parity
    const size_t SQP = (size_t)CROWS * 256;       // seqc elements per parity

    int prep_elems = 400 * 256 + NN * 256 + 2 * 3 * 256 * 64;
    prep_kernel<<<(prep_elems + 255) / 256, 256, 0, stream>>>(
        conv_w, w_ih_f, w_ih_r, w_hh_f, w_hh_r, wT, wcat, wq);

    auto lenk = [](int k) { return (k < NCHK - 1) ? TCH : (TC - (NCHK - 1) * TCH); }; // 126 / 106

    // prologue A: conv_0 -> seqc[p0]
    fat_kernel<<<128, 256, 0, stream>>>(
        0, xg, wqp, b_hh_f, b_hh_r, clf_w, hst, ps2, 0, 0, 0,
        0, seqc, wcat, b_ih_f, b_ih_r, xg,
        128, x, wT, conv_b, seqc, 0, lenk(0));

    // prologue B: proj_0 (seqc[p0] -> xg[p0]) || conv_1 -> seqc[p1]
    fat_kernel<<<(lenk(0) / 2) * 12 + 128, 256, 0, stream>>>(
        0, xg, wqp, b_hh_f, b_hh_r, clf_w, hst, ps2, 0, 0, 0,
        (lenk(0) / 2) * 12, seqc, wcat, b_ih_f, b_ih_r, xg,
        128, x, wT, conv_b, seqc + SQP, TCH, lenk(1));

    // main loop: launch k = scan_k || proj_{k+1} || conv_{k+2}
    for (int k = 0; k < NCHK; ++k) {
        int lens = lenk(k);
        int np = (k + 1 < NCHK) ? (lenk(k + 1) / 2) * 12 : 0;
        int nc = (k + 2 < NCHK) ? 128 : 0;
        fat_kernel<<<128 + np + nc, 256, 0, stream>>>(
            128, xg + (size_t)(k & 1) * XGP, wqp, b_hh_f, b_hh_r, clf_w, hst, ps2,
            k * TCH, lens, (k == 0) ? 1 : 0,
            np, seqc + (size_t)((k + 1) & 1) * SQP, wcat, b_ih_f, b_ih_r,
            xg + (size_t)((k + 1) & 1) * XGP,
            nc, x, wT, conv_b, seqc + (size_t)(k & 1) * SQP,
            (k + 2) * TCH, (k + 2 < NCHK) ? lenk(k + 2) : 0);
    }

    final_kernel<<<(TOUT * 128 + 255) / 256, 256, 0, stream>>>(ps2, clf_b, win, out);
}